// Round 6
// baseline (380.582 us; speedup 1.0000x reference)
//
#include <hip/hip_runtime.h>

// Problem constants
constexpr int B_ = 8, H_ = 64, W_ = 64, C0 = 16, D_ = 128, K_ = 8192;
constexpr int N_ = B_ * H_ * W_;  // 32768 pixels

typedef __attribute__((ext_vector_type(8))) short short8;  // 8 bf16
typedef __attribute__((ext_vector_type(4))) float f32x4;   // MFMA C/D

__device__ __forceinline__ float gelu_f(float x) {
    return 0.5f * x * (1.0f + erff(x * 0.70710678118654752440f));
}

__device__ __forceinline__ unsigned short f2bf(float f) {  // RNE f32->bf16
    unsigned u = __float_as_uint(f);
    u += 0x7fffu + ((u >> 16) & 1u);
    return (unsigned short)(u >> 16);
}

// ---------------------------------------------------------------------------
// One fused prep kernel (block-range switched):
//  A [0,2048):      x NCHW f32 -> xtbf NHWC bf16
//  B [2048,2624):   ew2 OIHW -> wtbf2 [t][co][ci] bf16
//  C [2624,3200):   dw1 OIHW -> wtbf3 [t][co][ci] bf16
//  D [3200,3232):   e2n[k] = -0.5*||embed_k||^2 (fp32)
//  E [3232,4256):   embed f32 -> embbf bf16
//  F [4256,4336):   ew1 OIHW -> wtb1b [co][kk=t*16+ci, pad 160] bf16
//  G [4336,4464):   partial[n] = 0 (VQ cross-block atomic-merge slots)
__global__ __launch_bounds__(256) void prep_kernel(
    const float* __restrict__ x, const float* __restrict__ ew1,
    const float* __restrict__ ew2, const float* __restrict__ dw1,
    const float* __restrict__ embed, unsigned short* __restrict__ xtbf,
    unsigned short* __restrict__ wtbf2, unsigned short* __restrict__ wtbf3,
    float* __restrict__ e2n, unsigned short* __restrict__ embbf,
    unsigned short* __restrict__ wtb1b,
    unsigned long long* __restrict__ partial) {
    int blk = blockIdx.x;
    int tid = threadIdx.x;
    if (blk < 2048) {  // A: xtbf (out-contiguous)
        int j = blk * 256 + tid;
        int c = j & 15, w = (j >> 4) & 63, h = (j >> 10) & 63, b = j >> 16;
        xtbf[j] = f2bf(x[(((b << 4) + c) << 12) + (h << 6) + w]);
    } else if (blk < 3200) {  // B/C: 3x3 128-ch weights -> [t][co][ci] bf16
        const float* src = (blk < 2624) ? ew2 : dw1;
        unsigned short* dst = (blk < 2624) ? wtbf2 : wtbf3;
        int i = (blk - ((blk < 2624) ? 2048 : 2624)) * 256 + tid;
        int ci = i & 127, co = (i >> 7) & 127, t = i >> 14;
        dst[i] = f2bf(src[(co * 128 + ci) * 9 + t]);
    } else if (blk < 3232) {  // D: e2n = -||e||^2 / 2
        int k = (blk - 3200) * 256 + tid;
        const float4* e4 = (const float4*)(embed + (size_t)k * 128);
        float s = 0.0f;
#pragma unroll 8
        for (int i = 0; i < 32; ++i) {
            float4 v = e4[i];
            s += v.x * v.x + v.y * v.y + v.z * v.z + v.w * v.w;
        }
        e2n[k] = -0.5f * s;
    } else if (blk < 4256) {  // E: embbf
        int i = (blk - 3232) * 256 + tid;
        float4 v = ((const float4*)embed)[i];
        uint2 o;
        o.x = (unsigned)f2bf(v.x) | ((unsigned)f2bf(v.y) << 16);
        o.y = (unsigned)f2bf(v.z) | ((unsigned)f2bf(v.w) << 16);
        ((uint2*)embbf)[i] = o;
    } else if (blk < 4336) {  // F: wtb1b [128 co][160 kk]
        int i = (blk - 4256) * 256 + tid;  // < 20480
        int co = i / 160, kk = i % 160;
        float v = 0.0f;
        if (kk < 144) {
            int t = kk >> 4, ci = kk & 15;
            v = ew1[(co * 16 + ci) * 9 + t];
        }
        wtb1b[i] = f2bf(v);
    } else {  // G: zero the VQ merge slots (poisoned 0xAA by harness)
        int i = (blk - 4336) * 256 + tid;  // < 32768
        partial[i] = 0ULL;
    }
}

// ---------------------------------------------------------------------------
// conv1: 16->128 3x3 + GELU via MFMA, K=160 (9 taps x 16 ci, zero-padded).
// All 10 weight frags preloaded to regs before the staging barrier (latency
// fully hidden); MFMA loop touches LDS only.
__global__ __launch_bounds__(256, 2) void conv1_mfma_kernel(
    const unsigned short* __restrict__ xtbf,   // NHWC [B,64,64,16] bf16
    const unsigned short* __restrict__ wtb1b,  // [128][160] bf16
    const float* __restrict__ bias,            // [128]
    unsigned short* __restrict__ out) {        // NHWC [B,64,64,128] bf16
    constexpr int LDA = 168;
    __shared__ __align__(16) unsigned short As[64 * LDA];  // 21504 B
    int tid = threadIdx.x;
    int wv = tid >> 6, lane = tid & 63;
    int r = lane & 15, q = lane >> 4;
    int h0 = blockIdx.x & 63, b = blockIdx.x >> 6;

    // preload all weight frags (40 VGPRs) — covered by staging + barrier
    short8 bf1[5][2];
#pragma unroll
    for (int k = 0; k < 5; ++k)
#pragma unroll
        for (int ns = 0; ns < 2; ++ns)
            bf1[k][ns] = *(const short8*)(wtb1b + (wv * 32 + ns * 16 + r) * 160 +
                                          k * 32 + q * 8);

#pragma unroll
    for (int j = 0; j < 5; ++j) {
        int s = tid + j * 256;
        if (s < 1152) {
            int px = s / 18, rem = s % 18;
            int t = rem >> 1, half = rem & 1;
            int hh = h0 + t / 3 - 1, ww = px + t % 3 - 1;
            float4 v = make_float4(0.f, 0.f, 0.f, 0.f);
            if ((unsigned)hh < 64u && (unsigned)ww < 64u)
                v = *(const float4*)(xtbf + (((b * 64 + hh) * 64 + ww) << 4) +
                                     half * 8);
            *(float4*)(As + px * LDA + t * 16 + half * 8) = v;
        } else {
            int z = s - 1152;  // < 128
            int px = z >> 1, half = z & 1;
            *(float4*)(As + px * LDA + 144 + half * 8) =
                make_float4(0.f, 0.f, 0.f, 0.f);
        }
    }
    __syncthreads();

    f32x4 acc[4][2];
#pragma unroll
    for (int ms = 0; ms < 4; ++ms)
#pragma unroll
        for (int ns = 0; ns < 2; ++ns) acc[ms][ns] = (f32x4){0.f, 0.f, 0.f, 0.f};

#pragma unroll
    for (int k = 0; k < 5; ++k) {
        short8 af[4];
#pragma unroll
        for (int ms = 0; ms < 4; ++ms)
            af[ms] = *(const short8*)(As + (ms * 16 + r) * LDA + k * 32 + q * 8);
#pragma unroll
        for (int ms = 0; ms < 4; ++ms)
#pragma unroll
            for (int ns = 0; ns < 2; ++ns)
                acc[ms][ns] = __builtin_amdgcn_mfma_f32_16x16x32_bf16(
                    af[ms], bf1[k][ns], acc[ms][ns], 0, 0, 0);
    }

#pragma unroll
    for (int ns = 0; ns < 2; ++ns) {
        int co = wv * 32 + ns * 16 + r;
        float bv = bias[co];
#pragma unroll
        for (int ms = 0; ms < 4; ++ms)
#pragma unroll
            for (int rg = 0; rg < 4; ++rg) {
                int px = ms * 16 + q * 4 + rg;
                int pix = (b * 64 + h0) * 64 + px;
                out[(size_t)pix * 128 + co] = f2bf(gelu_f(acc[ms][ns][rg] + bv));
            }
    }
}

// ---------------------------------------------------------------------------
// 3x3 128->128 conv + GELU via MFMA; halo staged once; weight frags ping-pong
// prefetched one k-group ahead (global->VGPR overlaps the 8 MFMAs).
// GATHER: A-pixels fetched through the packed VQ result (fused codebook
// gather). FUSE: dec2 (1x1 conv 128->16 + sigmoid) fused into the epilogue,
// writing the final NCHW fp32 output.
template <bool OUT_BF16, bool GATHER, bool FUSE>
__global__ __launch_bounds__(256, 2) void conv3x3_mfma_kernel(
    const unsigned short* __restrict__ in,   // NHWC acts, or embbf if GATHER
    const unsigned long long* __restrict__ gidx,  // packed VQ result or null
    const unsigned short* __restrict__ wtb,  // [9][co][ci] bf16
    const float* __restrict__ bias,          // [128]
    const float* __restrict__ w2,            // [16][128] fp32 (FUSE)
    const float* __restrict__ b2,            // [16] fp32 (FUSE)
    void* __restrict__ out_) {               // NHWC bf16/fp32, or NCHW if FUSE
    constexpr int LDC = 136;
    __shared__ __align__(16) unsigned short As[3 * 66 * LDC];  // 53856 B
    __shared__ __align__(16) float ws2[FUSE ? 2048 : 4];
    int tid = threadIdx.x;
    int wv = tid >> 6, lane = tid & 63;
    int r = lane & 15, q = lane >> 4;
    int h0 = blockIdx.x & 63, b = blockIdx.x >> 6;

    constexpr int NJ = FUSE ? 15 : 13;
    for (int j = 0; j < NJ; ++j) {
        int s = tid + j * 256;
        if (s < 3168) {
            int col = s >> 4, chunk = s & 15;
            int ry = col / 66, cx = col % 66;
            int hh = h0 - 1 + ry, ww = cx - 1;
            float4 v = make_float4(0.f, 0.f, 0.f, 0.f);
            if ((unsigned)hh < 64u && (unsigned)ww < 64u) {
                int pix = (b * 64 + hh) * 64 + ww;
                const unsigned short* src;
                if (GATHER) {
                    int k = 8191 - (int)(unsigned)(gidx[pix] & 0xFFFFFFFFu);
                    src = in + (size_t)k * 128;
                } else {
                    src = in + (size_t)pix * 128;
                }
                v = *(const float4*)(src + chunk * 8);
            }
            *(float4*)(As + col * LDC + chunk * 8) = v;
        } else if (FUSE && s < 3680) {
            int i = s - 3168;  // < 512 float4 slots
            ((float4*)ws2)[i] = ((const float4*)w2)[i];
        }
    }
    __syncthreads();

    f32x4 acc[4][2];
#pragma unroll
    for (int ms = 0; ms < 4; ++ms)
#pragma unroll
        for (int ns = 0; ns < 2; ++ns) acc[ms][ns] = (f32x4){0.f, 0.f, 0.f, 0.f};

    // weight ping-pong: groups g = t*4 + k, prefetch g+1 during g's MFMAs
    const unsigned short* wbase = wtb + (wv * 32 + r) * 128 + q * 8;
    short8 bfp[2][2];
    bfp[0][0] = *(const short8*)(wbase);
    bfp[0][1] = *(const short8*)(wbase + 2048);
    int gcur = 0;
    for (int t = 0; t < 9; ++t) {
        int dy = t / 3, dx = t % 3;
#pragma unroll
        for (int k = 0; k < 4; ++k) {
            int cur = gcur & 1, nxt = cur ^ 1;
            if (gcur < 35) {
                int g1 = gcur + 1;
                int t1 = g1 >> 2, k1 = g1 & 3;
                const unsigned short* wp = wbase + t1 * 16384 + k1 * 32;
                bfp[nxt][0] = *(const short8*)(wp);
                bfp[nxt][1] = *(const short8*)(wp + 2048);
            }
            short8 af[4];
#pragma unroll
            for (int ms = 0; ms < 4; ++ms) {
                int col = dy * 66 + ms * 16 + r + dx;
                af[ms] = *(const short8*)(As + col * LDC + k * 32 + q * 8);
            }
#pragma unroll
            for (int ms = 0; ms < 4; ++ms)
#pragma unroll
                for (int ns = 0; ns < 2; ++ns)
                    acc[ms][ns] = __builtin_amdgcn_mfma_f32_16x16x32_bf16(
                        af[ms], bfp[cur][ns], acc[ms][ns], 0, 0, 0);
            ++gcur;
        }
    }

    if (!FUSE) {
#pragma unroll
        for (int ns = 0; ns < 2; ++ns) {
            int co = wv * 32 + ns * 16 + r;
            float bv = bias[co];
#pragma unroll
            for (int ms = 0; ms < 4; ++ms)
#pragma unroll
                for (int rg = 0; rg < 4; ++rg) {
                    int px = ms * 16 + q * 4 + rg;
                    int pix = (b * 64 + h0) * 64 + px;
                    float g = gelu_f(acc[ms][ns][rg] + bv);
                    if (OUT_BF16)
                        ((unsigned short*)out_)[(size_t)pix * 128 + co] = f2bf(g);
                    else
                        ((float*)out_)[(size_t)pix * 128 + co] = g;
                }
        }
    } else {
        // bias+GELU -> LDS (reuse As as float[64][130]), then 1x1+sigmoid
        __syncthreads();  // all af reads done before overwrite
        float* gbuf = (float*)As;
#pragma unroll
        for (int ns = 0; ns < 2; ++ns) {
            int co = wv * 32 + ns * 16 + r;
            float bv = bias[co];
#pragma unroll
            for (int ms = 0; ms < 4; ++ms)
#pragma unroll
                for (int rg = 0; rg < 4; ++rg) {
                    int px = ms * 16 + q * 4 + rg;
                    gbuf[px * 130 + co] = gelu_f(acc[ms][ns][rg] + bv);
                }
        }
        __syncthreads();
        int w_ = tid & 63, c0 = (tid >> 6) * 4;
        float a4[4] = {b2[c0], b2[c0 + 1], b2[c0 + 2], b2[c0 + 3]};
#pragma unroll 1
        for (int ci = 0; ci < 128; ci += 2) {
            float2 yv = *(const float2*)&gbuf[w_ * 130 + ci];
#pragma unroll
            for (int jc = 0; jc < 4; ++jc) {
                float2 wv2 = *(const float2*)&ws2[(c0 + jc) * 128 + ci];
                a4[jc] += yv.x * wv2.x + yv.y * wv2.y;
            }
        }
        float* outp = (float*)out_;
#pragma unroll
        for (int jc = 0; jc < 4; ++jc) {
            float v = 1.0f / (1.0f + expf(-a4[jc]));
            outp[(((size_t)b * 16 + c0 + jc) * 64 + h0) * 64 + w_] = v;
        }
    }
}

// ---------------------------------------------------------------------------
// VQ argmin via bf16 MFMA, K-split x2 (1024 blocks). OCCUPANCY BUILD v6:
// Evidence model from rounds 0-5: __launch_bounds__(256,w) caps ARCH VGPRs
// at 256/w (acc goes to AGPR separately); HW occupancy = 512/(arch+acc).
// r1 proved 4 waves/SIMD is reachable (45% occ at 64+64) but spilled; r5
// proved in-wave pipelining (counted vmcnt) is NULL at 2 waves — the wall is
// TLP. v6 geometry: acc[2][4]=32 AGPR (ms=2: each wave owns 32 pixels) and
// the code range split across wave pairs: wv&1 = pixel-half, wv>>1 = code
// stream (32 its x 64 codes). Arch state: bf dbuf 32 + af 8 + best 8 +
// e2v 4 + addr ~20 = ~72 <= 85 (w=3 cap) -> no spill, total ~105-117 ->
// 4 waves/SIMD, 4 blocks/CU, grid = exactly one round.
// 11-bit key (it 5b, ns 2b, r 4b) in low mantissa (12 mantissa bits kept);
// larger packed = smaller code index on score tie (argmin tie-break).
// Cross-stream merge via LDS; cross-block: atomicMax on
// (sortable_score<<32 | (8191-code)).
__global__ __launch_bounds__(256, 3) void vq_mfma_kernel(
    const unsigned short* __restrict__ flatbf,  // [N][128] bf16
    const unsigned short* __restrict__ embbf,   // [K][128] bf16
    const float* __restrict__ e2n,              // [K] fp32, -||e||^2/2
    unsigned long long* __restrict__ partial) { // [N] packed, zero-inited
    constexpr int LDA = 136;
    __shared__ __align__(16) unsigned short As[64 * LDA];   // 17408 B
    __shared__ unsigned long long merged[64][2];            // 1024 B
    int tid = threadIdx.x;
    int wv = tid >> 6, lane = tid & 63;
    int r = lane & 15, q = lane >> 4;
    int p_h = wv & 1;       // pixel half: rows p_h*32 .. p_h*32+31
    int c_h = wv >> 1;      // code stream: 2048 codes each
    int half = blockIdx.x & 1;
    int m0 = (blockIdx.x >> 1) * 64;
    int kbase = half * 4096;

    // stage A (64 px x 128 d) to LDS (shared across the 4 waves)
#pragma unroll
    for (int j = 0; j < 4; ++j) {
        int row = j * 16 + (tid >> 4), col = tid & 15;
        float4 v = *(const float4*)(flatbf + (size_t)(m0 + row) * 128 + col * 8);
        *(float4*)(As + row * LDA + col * 8) = v;
    }
    __syncthreads();

    // this wave: codes kbase + c_h*2048 + it*64 + ns*16 + r, it in [0,32)
    const unsigned short* bp =
        embbf + (size_t)(kbase + c_h * 2048 + r) * 128 + q * 8;
    const float* e2p = e2n + kbase + c_h * 2048 + r;

    float best[2][4];
#pragma unroll
    for (int ms = 0; ms < 2; ++ms)
#pragma unroll
        for (int rg = 0; rg < 4; ++rg) best[ms][rg] = -3.4e38f;

    short8 bf[2][4];
    float e2v[4];
    // prologue: group-0 B frags + e2n for it=0
#pragma unroll
    for (int ns = 0; ns < 4; ++ns) bf[0][ns] = *(const short8*)(bp + ns * 2048);
#pragma unroll
    for (int ns = 0; ns < 4; ++ns) e2v[ns] = e2p[ns * 16];

    f32x4 acc[2][4];
#pragma unroll
    for (int ns = 0; ns < 4; ++ns) {
        float v = e2v[ns];
#pragma unroll
        for (int ms = 0; ms < 2; ++ms) acc[ms][ns] = (f32x4){v, v, v, v};
    }

    int key0 = 2047 - r;
#pragma unroll 4
    for (int g = 0; g < 128; ++g) {
        int cur = g & 1, nxt = cur ^ 1;
        int it = g >> 2, kk = g & 3;
        if (g < 127) {  // prefetch next B frags (L2-resident codebook)
            int g1 = g + 1;
            int it1 = g1 >> 2, kk1 = g1 & 3;
#pragma unroll
            for (int ns = 0; ns < 4; ++ns)
                bf[nxt][ns] = *(const short8*)(bp + (size_t)it1 * 8192 +
                                               ns * 2048 + kk1 * 32);
        }
        if (kk == 2 && it < 31) {  // e2n for next iter (consumed at reinit)
#pragma unroll
            for (int ns = 0; ns < 4; ++ns)
                e2v[ns] = e2p[(it + 1) * 64 + ns * 16];
        }
        // A frags from LDS (latency hidden by 4-wave TLP)
        short8 af[2];
#pragma unroll
        for (int ms = 0; ms < 2; ++ms)
            af[ms] = *(const short8*)(As + (p_h * 32 + ms * 16 + r) * LDA +
                                      kk * 32 + q * 8);
#pragma unroll
        for (int ms = 0; ms < 2; ++ms)
#pragma unroll
            for (int ns = 0; ns < 4; ++ns)
                acc[ms][ns] = __builtin_amdgcn_mfma_f32_16x16x32_bf16(
                    af[ms], bf[cur][ns], acc[ms][ns], 0, 0, 0);
        if (kk == 3) {
            // epilogue: pack 11-bit key, running max over 4 ns via fmax tree
            unsigned kb = (unsigned)(key0 - it * 64);
#pragma unroll
            for (int ms = 0; ms < 2; ++ms)
#pragma unroll
                for (int rg = 0; rg < 4; ++rg) {
                    float u0 = __uint_as_float(
                        (__float_as_uint(acc[ms][0][rg]) & 0xFFFFF800u) | kb);
                    float u1 = __uint_as_float(
                        (__float_as_uint(acc[ms][1][rg]) & 0xFFFFF800u) |
                        (kb - 16u));
                    float u2 = __uint_as_float(
                        (__float_as_uint(acc[ms][2][rg]) & 0xFFFFF800u) |
                        (kb - 32u));
                    float u3 = __uint_as_float(
                        (__float_as_uint(acc[ms][3][rg]) & 0xFFFFF800u) |
                        (kb - 48u));
                    best[ms][rg] = fmaxf(
                        best[ms][rg], fmaxf(fmaxf(u0, u1), fmaxf(u2, u3)));
                }
            if (it < 31) {  // reinit acc for next iter
#pragma unroll
                for (int ns = 0; ns < 4; ++ns) {
                    float v = e2v[ns];
#pragma unroll
                    for (int ms = 0; ms < 2; ++ms)
                        acc[ms][ns] = (f32x4){v, v, v, v};
                }
            }
        }
    }

    // in-wave merge over the 16 r-lanes (key encodes it,ns,r -> recoverable)
#pragma unroll
    for (int ms = 0; ms < 2; ++ms)
#pragma unroll
        for (int rg = 0; rg < 4; ++rg) {
            float v = best[ms][rg];
#pragma unroll
            for (int m = 1; m < 16; m <<= 1)
                v = fmaxf(v, __shfl_xor(v, m));
            best[ms][rg] = v;
        }
    if (r == 0) {
#pragma unroll
        for (int ms = 0; ms < 2; ++ms)
#pragma unroll
            for (int rg = 0; rg < 4; ++rg) {
                unsigned bits = __float_as_uint(best[ms][rg]);
                int cand = 2047 - (int)(bits & 2047u);  // it*64 + ns*16 + r
                int code = kbase + c_h * 2048 + (cand >> 6) * 64 +
                           ((cand >> 4) & 3) * 16 + (cand & 15);
                unsigned sb =
                    (bits & 0x80000000u) ? ~bits : (bits | 0x80000000u);
                unsigned long long packed =
                    ((unsigned long long)sb << 32) | (unsigned)(8191 - code);
                merged[p_h * 32 + ms * 16 + q * 4 + rg][c_h] = packed;
            }
    }
    __syncthreads();
    if (tid < 64) {
        unsigned long long bp0 = merged[tid][0];
        bp0 = bp0 > merged[tid][1] ? bp0 : merged[tid][1];
        atomicMax(partial + m0 + tid, bp0);
    }
}

// ---------------------------------------------------------------------------
extern "C" void kernel_launch(void* const* d_in, const int* in_sizes, int n_in,
                              void* d_out, int out_size, void* d_ws,
                              size_t ws_size, hipStream_t stream) {
    const float* x = (const float*)d_in[0];
    const float* ew1 = (const float*)d_in[1];
    const float* eb1 = (const float*)d_in[2];
    const float* ew2 = (const float*)d_in[3];
    const float* eb2 = (const float*)d_in[4];
    const float* embed = (const float*)d_in[5];
    const float* dw1 = (const float*)d_in[6];
    const float* db1 = (const float*)d_in[7];
    const float* dw2 = (const float*)d_in[8];
    const float* db2 = (const float*)d_in[9];
    float* out = (float*)d_out;

    float* e2n = (float*)d_ws;                             // 8192 f
    unsigned long long* partial =
        (unsigned long long*)(e2n + 8192);                 // 32768 u64
    unsigned short* xtbf = (unsigned short*)(partial + 32768);  // 524288 us
    unsigned short* wtb1b = xtbf + 524288;                 // 20480 us
    unsigned short* wtbf2 = wtb1b + 20480;                 // 147456 us
    unsigned short* wtbf3 = wtbf2 + 147456;                // 147456 us
    unsigned short* embbf = wtbf3 + 147456;                // 1048576 us
    unsigned short* abf = embbf + 1048576;                 // 4194304 us
    unsigned short* flatbf = abf + 4194304;                // 4194304 us

    prep_kernel<<<4464, 256, 0, stream>>>(x, ew1, ew2, dw1, embed, xtbf, wtbf2,
                                          wtbf3, e2n, embbf, wtb1b, partial);
    conv1_mfma_kernel<<<512, 256, 0, stream>>>(xtbf, wtb1b, eb1, abf);
    conv3x3_mfma_kernel<true, false, false><<<512, 256, 0, stream>>>(
        abf, nullptr, wtbf2, eb2, nullptr, nullptr, flatbf);
    vq_mfma_kernel<<<1024, 256, 0, stream>>>(flatbf, embbf, e2n, partial);
    conv3x3_mfma_kernel<false, true, true><<<512, 256, 0, stream>>>(
        embbf, partial, wtbf3, db1, dw2, db2, out);
}

// Round 7
// 223.007 us; speedup vs baseline: 1.7066x; 1.7066x over previous
//
#include <hip/hip_runtime.h>

// Problem constants
constexpr int B_ = 8, H_ = 64, W_ = 64, C0 = 16, D_ = 128, K_ = 8192;
constexpr int N_ = B_ * H_ * W_;  // 32768 pixels

typedef __attribute__((ext_vector_type(8))) short short8;  // 8 bf16
typedef __attribute__((ext_vector_type(4))) float f32x4;   // MFMA C/D

__device__ __forceinline__ float gelu_f(float x) {
    return 0.5f * x * (1.0f + erff(x * 0.70710678118654752440f));
}

__device__ __forceinline__ unsigned short f2bf(float f) {  // RNE f32->bf16
    unsigned u = __float_as_uint(f);
    u += 0x7fffu + ((u >> 16) & 1u);
    return (unsigned short)(u >> 16);
}

// async global->LDS DMA, 16 B per lane (dest = uniform base + lane*16)
__device__ __forceinline__ void gload_lds16(const void* g, void* l) {
    __builtin_amdgcn_global_load_lds(
        (const __attribute__((address_space(1))) unsigned int*)g,
        (__attribute__((address_space(3))) unsigned int*)l, 16, 0, 0);
}

// ---------------------------------------------------------------------------
// One fused prep kernel (block-range switched):
//  A [0,2048):      x NCHW f32 -> xtbf NHWC bf16
//  B [2048,2624):   ew2 OIHW -> wtbf2 [t][co][ci] bf16
//  C [2624,3200):   dw1 OIHW -> wtbf3 [t][co][ci] bf16
//  D [3200,3232):   e2n[k] = -0.5*||embed_k||^2 (fp32)
//  E [3232,4256):   embed f32 -> embbf bf16 (decoder gather)
//  F [4256,4336):   ew1 OIHW -> wtb1b [co][kk=t*16+ci, pad 160] bf16
//  G [4336,4464):   partial[n] = 0 (VQ cross-block atomic-merge slots)
//  H [4464,4976):   embq: codebook reordered into MFMA fragment order
//                   [tile64][kk][ns4][r16][q4][8e] (16 KB per 64-code tile)
__global__ __launch_bounds__(256) void prep_kernel(
    const float* __restrict__ x, const float* __restrict__ ew1,
    const float* __restrict__ ew2, const float* __restrict__ dw1,
    const float* __restrict__ embed, unsigned short* __restrict__ xtbf,
    unsigned short* __restrict__ wtbf2, unsigned short* __restrict__ wtbf3,
    float* __restrict__ e2n, unsigned short* __restrict__ embbf,
    unsigned short* __restrict__ wtb1b,
    unsigned long long* __restrict__ partial,
    unsigned short* __restrict__ embq) {
    int blk = blockIdx.x;
    int tid = threadIdx.x;
    if (blk < 2048) {  // A: xtbf (out-contiguous)
        int j = blk * 256 + tid;
        int c = j & 15, w = (j >> 4) & 63, h = (j >> 10) & 63, b = j >> 16;
        xtbf[j] = f2bf(x[(((b << 4) + c) << 12) + (h << 6) + w]);
    } else if (blk < 3200) {  // B/C: 3x3 128-ch weights -> [t][co][ci] bf16
        const float* src = (blk < 2624) ? ew2 : dw1;
        unsigned short* dst = (blk < 2624) ? wtbf2 : wtbf3;
        int i = (blk - ((blk < 2624) ? 2048 : 2624)) * 256 + tid;
        int ci = i & 127, co = (i >> 7) & 127, t = i >> 14;
        dst[i] = f2bf(src[(co * 128 + ci) * 9 + t]);
    } else if (blk < 3232) {  // D: e2n = -||e||^2 / 2
        int k = (blk - 3200) * 256 + tid;
        const float4* e4 = (const float4*)(embed + (size_t)k * 128);
        float s = 0.0f;
#pragma unroll 8
        for (int i = 0; i < 32; ++i) {
            float4 v = e4[i];
            s += v.x * v.x + v.y * v.y + v.z * v.z + v.w * v.w;
        }
        e2n[k] = -0.5f * s;
    } else if (blk < 4256) {  // E: embbf
        int i = (blk - 3232) * 256 + tid;
        float4 v = ((const float4*)embed)[i];
        uint2 o;
        o.x = (unsigned)f2bf(v.x) | ((unsigned)f2bf(v.y) << 16);
        o.y = (unsigned)f2bf(v.z) | ((unsigned)f2bf(v.w) << 16);
        ((uint2*)embbf)[i] = o;
    } else if (blk < 4336) {  // F: wtb1b [128 co][160 kk]
        int i = (blk - 4256) * 256 + tid;  // < 20480
        int co = i / 160, kk = i % 160;
        float v = 0.0f;
        if (kk < 144) {
            int t = kk >> 4, ci = kk & 15;
            v = ew1[(co * 16 + ci) * 9 + t];
        }
        wtb1b[i] = f2bf(v);
    } else if (blk < 4464) {  // G: zero the VQ merge slots
        int i = (blk - 4336) * 256 + tid;  // < 32768
        partial[i] = 0ULL;
    } else {  // H: embq fragment reorder (one 16-B slot per thread)
        int s = (blk - 4464) * 256 + tid;  // < 131072 slots
        int T = s >> 10;
        int rem = s & 1023;
        int kk = rem >> 8, nsp = (rem >> 6) & 3, r = (rem >> 2) & 15,
            q = rem & 3;
        int code = T * 64 + nsp * 16 + r;
        int d0 = kk * 32 + q * 8;
        const float* ep = embed + (size_t)code * 128 + d0;
        unsigned short* op = embq + (size_t)s * 8;
#pragma unroll
        for (int e = 0; e < 8; ++e) op[e] = f2bf(ep[e]);
    }
}

// ---------------------------------------------------------------------------
// conv1: 16->128 3x3 + GELU via MFMA, K=160 (9 taps x 16 ci, zero-padded).
// All 10 weight frags preloaded to regs before the staging barrier (latency
// fully hidden); MFMA loop touches LDS only.
__global__ __launch_bounds__(256, 2) void conv1_mfma_kernel(
    const unsigned short* __restrict__ xtbf,   // NHWC [B,64,64,16] bf16
    const unsigned short* __restrict__ wtb1b,  // [128][160] bf16
    const float* __restrict__ bias,            // [128]
    unsigned short* __restrict__ out) {        // NHWC [B,64,64,128] bf16
    constexpr int LDA = 168;
    __shared__ __align__(16) unsigned short As[64 * LDA];  // 21504 B
    int tid = threadIdx.x;
    int wv = tid >> 6, lane = tid & 63;
    int r = lane & 15, q = lane >> 4;
    int h0 = blockIdx.x & 63, b = blockIdx.x >> 6;

    // preload all weight frags (40 VGPRs) — covered by staging + barrier
    short8 bf1[5][2];
#pragma unroll
    for (int k = 0; k < 5; ++k)
#pragma unroll
        for (int ns = 0; ns < 2; ++ns)
            bf1[k][ns] = *(const short8*)(wtb1b + (wv * 32 + ns * 16 + r) * 160 +
                                          k * 32 + q * 8);

#pragma unroll
    for (int j = 0; j < 5; ++j) {
        int s = tid + j * 256;
        if (s < 1152) {
            int px = s / 18, rem = s % 18;
            int t = rem >> 1, half = rem & 1;
            int hh = h0 + t / 3 - 1, ww = px + t % 3 - 1;
            float4 v = make_float4(0.f, 0.f, 0.f, 0.f);
            if ((unsigned)hh < 64u && (unsigned)ww < 64u)
                v = *(const float4*)(xtbf + (((b * 64 + hh) * 64 + ww) << 4) +
                                     half * 8);
            *(float4*)(As + px * LDA + t * 16 + half * 8) = v;
        } else {
            int z = s - 1152;  // < 128
            int px = z >> 1, half = z & 1;
            *(float4*)(As + px * LDA + 144 + half * 8) =
                make_float4(0.f, 0.f, 0.f, 0.f);
        }
    }
    __syncthreads();

    f32x4 acc[4][2];
#pragma unroll
    for (int ms = 0; ms < 4; ++ms)
#pragma unroll
        for (int ns = 0; ns < 2; ++ns) acc[ms][ns] = (f32x4){0.f, 0.f, 0.f, 0.f};

#pragma unroll
    for (int k = 0; k < 5; ++k) {
        short8 af[4];
#pragma unroll
        for (int ms = 0; ms < 4; ++ms)
            af[ms] = *(const short8*)(As + (ms * 16 + r) * LDA + k * 32 + q * 8);
#pragma unroll
        for (int ms = 0; ms < 4; ++ms)
#pragma unroll
            for (int ns = 0; ns < 2; ++ns)
                acc[ms][ns] = __builtin_amdgcn_mfma_f32_16x16x32_bf16(
                    af[ms], bf1[k][ns], acc[ms][ns], 0, 0, 0);
    }

#pragma unroll
    for (int ns = 0; ns < 2; ++ns) {
        int co = wv * 32 + ns * 16 + r;
        float bv = bias[co];
#pragma unroll
        for (int ms = 0; ms < 4; ++ms)
#pragma unroll
            for (int rg = 0; rg < 4; ++rg) {
                int px = ms * 16 + q * 4 + rg;
                int pix = (b * 64 + h0) * 64 + px;
                out[(size_t)pix * 128 + co] = f2bf(gelu_f(acc[ms][ns][rg] + bv));
            }
    }
}

// ---------------------------------------------------------------------------
// 3x3 128->128 conv + GELU via MFMA; halo staged once; weight frags ping-pong
// prefetched one k-group ahead (global->VGPR overlaps the 8 MFMAs).
// GATHER: A-pixels fetched through the packed VQ result (fused codebook
// gather). FUSE: dec2 (1x1 conv 128->16 + sigmoid) fused into the epilogue,
// writing the final NCHW fp32 output.
template <bool OUT_BF16, bool GATHER, bool FUSE>
__global__ __launch_bounds__(256, 2) void conv3x3_mfma_kernel(
    const unsigned short* __restrict__ in,   // NHWC acts, or embbf if GATHER
    const unsigned long long* __restrict__ gidx,  // packed VQ result or null
    const unsigned short* __restrict__ wtb,  // [9][co][ci] bf16
    const float* __restrict__ bias,          // [128]
    const float* __restrict__ w2,            // [16][128] fp32 (FUSE)
    const float* __restrict__ b2,            // [16] fp32 (FUSE)
    void* __restrict__ out_) {               // NHWC bf16/fp32, or NCHW if FUSE
    constexpr int LDC = 136;
    __shared__ __align__(16) unsigned short As[3 * 66 * LDC];  // 53856 B
    __shared__ __align__(16) float ws2[FUSE ? 2048 : 4];
    int tid = threadIdx.x;
    int wv = tid >> 6, lane = tid & 63;
    int r = lane & 15, q = lane >> 4;
    int h0 = blockIdx.x & 63, b = blockIdx.x >> 6;

    constexpr int NJ = FUSE ? 15 : 13;
    for (int j = 0; j < NJ; ++j) {
        int s = tid + j * 256;
        if (s < 3168) {
            int col = s >> 4, chunk = s & 15;
            int ry = col / 66, cx = col % 66;
            int hh = h0 - 1 + ry, ww = cx - 1;
            float4 v = make_float4(0.f, 0.f, 0.f, 0.f);
            if ((unsigned)hh < 64u && (unsigned)ww < 64u) {
                int pix = (b * 64 + hh) * 64 + ww;
                const unsigned short* src;
                if (GATHER) {
                    int k = 8191 - (int)(unsigned)(gidx[pix] & 0xFFFFFFFFu);
                    src = in + (size_t)k * 128;
                } else {
                    src = in + (size_t)pix * 128;
                }
                v = *(const float4*)(src + chunk * 8);
            }
            *(float4*)(As + col * LDC + chunk * 8) = v;
        } else if (FUSE && s < 3680) {
            int i = s - 3168;  // < 512 float4 slots
            ((float4*)ws2)[i] = ((const float4*)w2)[i];
        }
    }
    __syncthreads();

    f32x4 acc[4][2];
#pragma unroll
    for (int ms = 0; ms < 4; ++ms)
#pragma unroll
        for (int ns = 0; ns < 2; ++ns) acc[ms][ns] = (f32x4){0.f, 0.f, 0.f, 0.f};

    // weight ping-pong: groups g = t*4 + k, prefetch g+1 during g's MFMAs
    const unsigned short* wbase = wtb + (wv * 32 + r) * 128 + q * 8;
    short8 bfp[2][2];
    bfp[0][0] = *(const short8*)(wbase);
    bfp[0][1] = *(const short8*)(wbase + 2048);
    int gcur = 0;
    for (int t = 0; t < 9; ++t) {
        int dy = t / 3, dx = t % 3;
#pragma unroll
        for (int k = 0; k < 4; ++k) {
            int cur = gcur & 1, nxt = cur ^ 1;
            if (gcur < 35) {
                int g1 = gcur + 1;
                int t1 = g1 >> 2, k1 = g1 & 3;
                const unsigned short* wp = wbase + t1 * 16384 + k1 * 32;
                bfp[nxt][0] = *(const short8*)(wp);
                bfp[nxt][1] = *(const short8*)(wp + 2048);
            }
            short8 af[4];
#pragma unroll
            for (int ms = 0; ms < 4; ++ms) {
                int col = dy * 66 + ms * 16 + r + dx;
                af[ms] = *(const short8*)(As + col * LDC + k * 32 + q * 8);
            }
#pragma unroll
            for (int ms = 0; ms < 4; ++ms)
#pragma unroll
                for (int ns = 0; ns < 2; ++ns)
                    acc[ms][ns] = __builtin_amdgcn_mfma_f32_16x16x32_bf16(
                        af[ms], bfp[cur][ns], acc[ms][ns], 0, 0, 0);
            ++gcur;
        }
    }

    if (!FUSE) {
#pragma unroll
        for (int ns = 0; ns < 2; ++ns) {
            int co = wv * 32 + ns * 16 + r;
            float bv = bias[co];
#pragma unroll
            for (int ms = 0; ms < 4; ++ms)
#pragma unroll
                for (int rg = 0; rg < 4; ++rg) {
                    int px = ms * 16 + q * 4 + rg;
                    int pix = (b * 64 + h0) * 64 + px;
                    float g = gelu_f(acc[ms][ns][rg] + bv);
                    if (OUT_BF16)
                        ((unsigned short*)out_)[(size_t)pix * 128 + co] = f2bf(g);
                    else
                        ((float*)out_)[(size_t)pix * 128 + co] = g;
                }
        }
    } else {
        // bias+GELU -> LDS (reuse As as float[64][130]), then 1x1+sigmoid
        __syncthreads();  // all af reads done before overwrite
        float* gbuf = (float*)As;
#pragma unroll
        for (int ns = 0; ns < 2; ++ns) {
            int co = wv * 32 + ns * 16 + r;
            float bv = bias[co];
#pragma unroll
            for (int ms = 0; ms < 4; ++ms)
#pragma unroll
                for (int rg = 0; rg < 4; ++rg) {
                    int px = ms * 16 + q * 4 + rg;
                    gbuf[px * 130 + co] = gelu_f(acc[ms][ns][rg] + bv);
                }
        }
        __syncthreads();
        int w_ = tid & 63, c0 = (tid >> 6) * 4;
        float a4[4] = {b2[c0], b2[c0 + 1], b2[c0 + 2], b2[c0 + 3]};
#pragma unroll 1
        for (int ci = 0; ci < 128; ci += 2) {
            float2 yv = *(const float2*)&gbuf[w_ * 130 + ci];
#pragma unroll
            for (int jc = 0; jc < 4; ++jc) {
                float2 wv2 = *(const float2*)&ws2[(c0 + jc) * 128 + ci];
                a4[jc] += yv.x * wv2.x + yv.y * wv2.y;
            }
        }
        float* outp = (float*)out_;
#pragma unroll
        for (int jc = 0; jc < 4; ++jc) {
            float v = 1.0f / (1.0f + expf(-a4[jc]));
            outp[(((size_t)b * 16 + c0 + jc) * 64 + h0) * 64 + w_] = v;
        }
    }
}

// ---------------------------------------------------------------------------
// VQ argmin via bf16 MFMA. LDS-STAGED GEMM BUILD v7.
// Rounds 0-6 evidence: wall = #K-groups x ~2000cy fixed per-group cost,
// invariant under in-wave prefetch depth (r0=r4=r5=137us) and scaling with
// group count (v6: 2x groups -> 1.8x time). Cause: per-wave 64-B-granular
// L2 gathers + no TLP. v7 = canonical LDS-staged GEMM:
//  - prep reorders codebook into fragment order (embq), so each 64-code
//    tile (16 KB) stages to LDS via 16 linear global_load_lds DMAs,
//    double-buffered; one __syncthreads per tile (implicit vmcnt drain).
//  - wave geometry 32px x 32codes: acc[2][2]=16 AGPR, af[4][2]=32 preloaded
//    from global once; per tile: 8 conflict-free ds_read_b128 + 16 MFMA.
//  - natural arch regs ~85 at __launch_bounds__(256,2) (no spill trap);
//    LDS 32 KB -> 4 blocks/CU = 4 waves/SIMD, grid = exactly one round.
//  - pixels per wave exclusive -> no LDS merge; r-lane shfl + atomicMax.
// Two 32-tile passes keep the 11-bit key / 0xFFFFF800 mask (validated v6).
// code = kbase + pass*2048 + cand. Cross-block: atomicMax on
// (sortable_score<<32 | (8191-code)).
__global__ __launch_bounds__(256, 2) void vq_mfma_kernel(
    const unsigned short* __restrict__ flatbf,  // [N][128] bf16
    const unsigned short* __restrict__ embq,    // fragment-ordered codebook
    const float* __restrict__ e2n,              // [K] fp32, -||e||^2/2
    unsigned long long* __restrict__ partial) { // [N] packed, zero-inited
    __shared__ __align__(16) unsigned short Bs[2][8192];  // 2 x 16 KB
    int tid = threadIdx.x;
    int wv = tid >> 6, lane = tid & 63;
    int r = lane & 15, q = lane >> 4;
    int p_h = wv & 1;   // pixel half: rows p_h*32 + ms*16 + ...
    int c_s = wv >> 1;  // code half of each 64-code tile
    int half = blockIdx.x & 1;
    int m0 = (blockIdx.x >> 1) * 64;
    int kbase = half * 4096;
    int t0 = half * 64;  // first tile index

    // A: 32 px x 128 dims preloaded to regs (8 gather loads, once)
    short8 af[4][2];
#pragma unroll
    for (int kk = 0; kk < 4; ++kk)
#pragma unroll
        for (int ms = 0; ms < 2; ++ms)
            af[kk][ms] = *(const short8*)(
                flatbf + (size_t)(m0 + p_h * 32 + ms * 16 + r) * 128 +
                kk * 32 + q * 8);

    const float* e2p = e2n + kbase + c_s * 32 + r;
    float e2a = e2p[0], e2b = e2p[16];  // it=0 init values
    float e2nx0 = 0.f, e2nx1 = 0.f;

    // stage tile 0 into Bs[0]
    {
        const unsigned short* src = embq + (size_t)t0 * 8192;
#pragma unroll
        for (int j = 0; j < 4; ++j) {
            int o = (j * 4 + wv) * 512;  // shorts (1 KB per DMA)
            gload_lds16(src + o + lane * 8, &Bs[0][o]);
        }
    }

    float best[2][4];
#pragma unroll
    for (int ms = 0; ms < 2; ++ms)
#pragma unroll
        for (int rg = 0; rg < 4; ++rg) best[ms][rg] = -3.4e38f;

    __syncthreads();  // tile 0 ready (barrier drains vmcnt)

    f32x4 acc[2][2];
#pragma unroll
    for (int ms = 0; ms < 2; ++ms) {
        acc[ms][0] = (f32x4){e2a, e2a, e2a, e2a};
        acc[ms][1] = (f32x4){e2b, e2b, e2b, e2b};
    }

    int cur = 0;
#pragma unroll 1
    for (int it = 0; it < 64; ++it) {
        if (it < 63) {  // stage tile it+1 into the other buffer
            const unsigned short* src = embq + (size_t)(t0 + it + 1) * 8192;
            unsigned short* dst = &Bs[cur ^ 1][0];
#pragma unroll
            for (int j = 0; j < 4; ++j) {
                int o = (j * 4 + wv) * 512;
                gload_lds16(src + o + lane * 8, dst + o);
            }
            // e2 for next tile (consumed at reinit, ~whole tile of lead)
            e2nx0 = e2p[(it + 1) * 64];
            e2nx1 = e2p[(it + 1) * 64 + 16];
        }
        const unsigned short* bb = &Bs[cur][0];
#pragma unroll
        for (int kk = 0; kk < 4; ++kk) {
            short8 bf0 = *(const short8*)(bb + kk * 2048 + (c_s * 2) * 512 +
                                          r * 32 + q * 8);
            short8 bf1 = *(const short8*)(bb + kk * 2048 + (c_s * 2 + 1) * 512 +
                                          r * 32 + q * 8);
#pragma unroll
            for (int ms = 0; ms < 2; ++ms) {
                acc[ms][0] = __builtin_amdgcn_mfma_f32_16x16x32_bf16(
                    af[kk][ms], bf0, acc[ms][0], 0, 0, 0);
                acc[ms][1] = __builtin_amdgcn_mfma_f32_16x16x32_bf16(
                    af[kk][ms], bf1, acc[ms][1], 0, 0, 0);
            }
        }
        // epilogue: pack 11-bit key (it5,c_s,ns,r), running max
        unsigned kb = (unsigned)(2047 - ((it & 31) * 64 + c_s * 32 + r));
#pragma unroll
        for (int ms = 0; ms < 2; ++ms)
#pragma unroll
            for (int rg = 0; rg < 4; ++rg) {
                float u0 = __uint_as_float(
                    (__float_as_uint(acc[ms][0][rg]) & 0xFFFFF800u) | kb);
                float u1 = __uint_as_float(
                    (__float_as_uint(acc[ms][1][rg]) & 0xFFFFF800u) |
                    (kb - 16u));
                best[ms][rg] = fmaxf(best[ms][rg], fmaxf(u0, u1));
            }
        if ((it & 31) == 31) {  // pass end: merge r-lanes, atomic, reset
#pragma unroll
            for (int ms = 0; ms < 2; ++ms)
#pragma unroll
                for (int rg = 0; rg < 4; ++rg) {
                    float v = best[ms][rg];
#pragma unroll
                    for (int m = 1; m < 16; m <<= 1)
                        v = fmaxf(v, __shfl_xor(v, m));
                    if (r == 0) {
                        unsigned bits = __float_as_uint(v);
                        int cand = 2047 - (int)(bits & 2047u);
                        int code = kbase + (it >> 5) * 2048 + cand;
                        unsigned sb = (bits & 0x80000000u) ? ~bits
                                                           : (bits | 0x80000000u);
                        unsigned long long packed =
                            ((unsigned long long)sb << 32) |
                            (unsigned)(8191 - code);
                        atomicMax(
                            partial + m0 + p_h * 32 + ms * 16 + q * 4 + rg,
                            packed);
                    }
                    best[ms][rg] = -3.4e38f;
                }
        }
        if (it < 63) {  // reinit acc for next tile's codes
#pragma unroll
            for (int ms = 0; ms < 2; ++ms) {
                acc[ms][0] = (f32x4){e2nx0, e2nx0, e2nx0, e2nx0};
                acc[ms][1] = (f32x4){e2nx1, e2nx1, e2nx1, e2nx1};
            }
        }
        __syncthreads();  // staging done + all reads of Bs[cur] done
        cur ^= 1;
    }
}

// ---------------------------------------------------------------------------
extern "C" void kernel_launch(void* const* d_in, const int* in_sizes, int n_in,
                              void* d_out, int out_size, void* d_ws,
                              size_t ws_size, hipStream_t stream) {
    const float* x = (const float*)d_in[0];
    const float* ew1 = (const float*)d_in[1];
    const float* eb1 = (const float*)d_in[2];
    const float* ew2 = (const float*)d_in[3];
    const float* eb2 = (const float*)d_in[4];
    const float* embed = (const float*)d_in[5];
    const float* dw1 = (const float*)d_in[6];
    const float* db1 = (const float*)d_in[7];
    const float* dw2 = (const float*)d_in[8];
    const float* db2 = (const float*)d_in[9];
    float* out = (float*)d_out;

    float* e2n = (float*)d_ws;                             // 8192 f
    unsigned long long* partial =
        (unsigned long long*)(e2n + 8192);                 // 32768 u64
    unsigned short* xtbf = (unsigned short*)(partial + 32768);  // 524288 us
    unsigned short* wtb1b = xtbf + 524288;                 // 20480 us
    unsigned short* wtbf2 = wtb1b + 20480;                 // 147456 us
    unsigned short* wtbf3 = wtbf2 + 147456;                // 147456 us
    unsigned short* embbf = wtbf3 + 147456;                // 1048576 us
    unsigned short* abf = embbf + 1048576;                 // 4194304 us
    unsigned short* flatbf = abf + 4194304;                // 4194304 us
    unsigned short* embq = flatbf + 4194304;               // 1048576 us

    prep_kernel<<<4976, 256, 0, stream>>>(x, ew1, ew2, dw1, embed, xtbf, wtbf2,
                                          wtbf3, e2n, embbf, wtb1b, partial,
                                          embq);
    conv1_mfma_kernel<<<512, 256, 0, stream>>>(xtbf, wtb1b, eb1, abf);
    conv3x3_mfma_kernel<true, false, false><<<512, 256, 0, stream>>>(
        abf, nullptr, wtbf2, eb2, nullptr, nullptr, flatbf);
    vq_mfma_kernel<<<1024, 256, 0, stream>>>(flatbf, embq, e2n, partial);
    conv3x3_mfma_kernel<false, true, true><<<512, 256, 0, stream>>>(
        embbf, partial, wtbf3, db1, dw2, db2, out);
}

// Round 8
// 222.731 us; speedup vs baseline: 1.7087x; 1.0012x over previous
//
#include <hip/hip_runtime.h>

// Problem constants
constexpr int B_ = 8, H_ = 64, W_ = 64, C0 = 16, D_ = 128, K_ = 8192;
constexpr int N_ = B_ * H_ * W_;  // 32768 pixels

typedef __attribute__((ext_vector_type(8))) short short8;  // 8 bf16
typedef __attribute__((ext_vector_type(4))) float f32x4;   // MFMA C/D

__device__ __forceinline__ float gelu_f(float x) {
    return 0.5f * x * (1.0f + erff(x * 0.70710678118654752440f));
}

__device__ __forceinline__ unsigned short f2bf(float f) {  // RNE f32->bf16
    unsigned u = __float_as_uint(f);
    u += 0x7fffu + ((u >> 16) & 1u);
    return (unsigned short)(u >> 16);
}

// async global->LDS DMA, 16 B per lane (dest = uniform base + lane*16)
__device__ __forceinline__ void gload_lds16(const void* g, void* l) {
    __builtin_amdgcn_global_load_lds(
        (const __attribute__((address_space(1))) unsigned int*)g,
        (__attribute__((address_space(3))) unsigned int*)l, 16, 0, 0);
}

// ---------------------------------------------------------------------------
// One fused prep kernel (block-range switched):
//  A [0,2048):      x NCHW f32 -> xtbf NHWC bf16
//  B [2048,2624):   ew2 OIHW -> wtbf2 [t][co][ci] bf16
//  C [2624,3200):   dw1 OIHW -> wtbf3 [t][co][ci] bf16
//  D [3200,3232):   e2n[k] = -0.5*||embed_k||^2 (fp32)
//  E [3232,4256):   embed f32 -> embbf bf16 (decoder gather)
//  F [4256,4336):   ew1 OIHW -> wtb1b [co][kk=t*16+ci, pad 160] bf16
//  G [4336,4464):   partial[n] = 0 (VQ cross-block atomic-merge slots)
//  H [4464,4976):   embq: codebook reordered into MFMA fragment order.
//                   v8 layout [tile64][kk4][ns4][q4][r16][8e]: vq's lane
//                   (r,q) then reads byte lane*16 within its ns-block ->
//                   64 lanes read 1024 CONTIGUOUS bytes, conflict-free
//                   (r7 layout [ns][r][q] strided 64B/lane-group = 8-way
//                   bank conflict, 8.39M conflict cycles).
__global__ __launch_bounds__(256) void prep_kernel(
    const float* __restrict__ x, const float* __restrict__ ew1,
    const float* __restrict__ ew2, const float* __restrict__ dw1,
    const float* __restrict__ embed, unsigned short* __restrict__ xtbf,
    unsigned short* __restrict__ wtbf2, unsigned short* __restrict__ wtbf3,
    float* __restrict__ e2n, unsigned short* __restrict__ embbf,
    unsigned short* __restrict__ wtb1b,
    unsigned long long* __restrict__ partial,
    unsigned short* __restrict__ embq) {
    int blk = blockIdx.x;
    int tid = threadIdx.x;
    if (blk < 2048) {  // A: xtbf (out-contiguous)
        int j = blk * 256 + tid;
        int c = j & 15, w = (j >> 4) & 63, h = (j >> 10) & 63, b = j >> 16;
        xtbf[j] = f2bf(x[(((b << 4) + c) << 12) + (h << 6) + w]);
    } else if (blk < 3200) {  // B/C: 3x3 128-ch weights -> [t][co][ci] bf16
        const float* src = (blk < 2624) ? ew2 : dw1;
        unsigned short* dst = (blk < 2624) ? wtbf2 : wtbf3;
        int i = (blk - ((blk < 2624) ? 2048 : 2624)) * 256 + tid;
        int ci = i & 127, co = (i >> 7) & 127, t = i >> 14;
        dst[i] = f2bf(src[(co * 128 + ci) * 9 + t]);
    } else if (blk < 3232) {  // D: e2n = -||e||^2 / 2
        int k = (blk - 3200) * 256 + tid;
        const float4* e4 = (const float4*)(embed + (size_t)k * 128);
        float s = 0.0f;
#pragma unroll 8
        for (int i = 0; i < 32; ++i) {
            float4 v = e4[i];
            s += v.x * v.x + v.y * v.y + v.z * v.z + v.w * v.w;
        }
        e2n[k] = -0.5f * s;
    } else if (blk < 4256) {  // E: embbf
        int i = (blk - 3232) * 256 + tid;
        float4 v = ((const float4*)embed)[i];
        uint2 o;
        o.x = (unsigned)f2bf(v.x) | ((unsigned)f2bf(v.y) << 16);
        o.y = (unsigned)f2bf(v.z) | ((unsigned)f2bf(v.w) << 16);
        ((uint2*)embbf)[i] = o;
    } else if (blk < 4336) {  // F: wtb1b [128 co][160 kk]
        int i = (blk - 4256) * 256 + tid;  // < 20480
        int co = i / 160, kk = i % 160;
        float v = 0.0f;
        if (kk < 144) {
            int t = kk >> 4, ci = kk & 15;
            v = ew1[(co * 16 + ci) * 9 + t];
        }
        wtb1b[i] = f2bf(v);
    } else if (blk < 4464) {  // G: zero the VQ merge slots
        int i = (blk - 4336) * 256 + tid;  // < 32768
        partial[i] = 0ULL;
    } else {  // H: embq fragment reorder (one 16-B slot per thread)
        int s = (blk - 4464) * 256 + tid;  // < 131072 slots
        int T = s >> 10;
        int rem = s & 1023;  // slot = ((kk*4 + ns)*4 + q)*16 + r
        int kk = rem >> 8, nsp = (rem >> 6) & 3, q = (rem >> 4) & 3,
            r = rem & 15;
        int code = T * 64 + nsp * 16 + r;
        int d0 = kk * 32 + q * 8;
        const float* ep = embed + (size_t)code * 128 + d0;
        unsigned short* op = embq + (size_t)s * 8;
#pragma unroll
        for (int e = 0; e < 8; ++e) op[e] = f2bf(ep[e]);
    }
}

// ---------------------------------------------------------------------------
// conv1: 16->128 3x3 + GELU via MFMA, K=160 (9 taps x 16 ci, zero-padded).
// All 10 weight frags preloaded to regs before the staging barrier (latency
// fully hidden); MFMA loop touches LDS only.
__global__ __launch_bounds__(256, 2) void conv1_mfma_kernel(
    const unsigned short* __restrict__ xtbf,   // NHWC [B,64,64,16] bf16
    const unsigned short* __restrict__ wtb1b,  // [128][160] bf16
    const float* __restrict__ bias,            // [128]
    unsigned short* __restrict__ out) {        // NHWC [B,64,64,128] bf16
    constexpr int LDA = 168;
    __shared__ __align__(16) unsigned short As[64 * LDA];  // 21504 B
    int tid = threadIdx.x;
    int wv = tid >> 6, lane = tid & 63;
    int r = lane & 15, q = lane >> 4;
    int h0 = blockIdx.x & 63, b = blockIdx.x >> 6;

    // preload all weight frags (40 VGPRs) — covered by staging + barrier
    short8 bf1[5][2];
#pragma unroll
    for (int k = 0; k < 5; ++k)
#pragma unroll
        for (int ns = 0; ns < 2; ++ns)
            bf1[k][ns] = *(const short8*)(wtb1b + (wv * 32 + ns * 16 + r) * 160 +
                                          k * 32 + q * 8);

#pragma unroll
    for (int j = 0; j < 5; ++j) {
        int s = tid + j * 256;
        if (s < 1152) {
            int px = s / 18, rem = s % 18;
            int t = rem >> 1, half = rem & 1;
            int hh = h0 + t / 3 - 1, ww = px + t % 3 - 1;
            float4 v = make_float4(0.f, 0.f, 0.f, 0.f);
            if ((unsigned)hh < 64u && (unsigned)ww < 64u)
                v = *(const float4*)(xtbf + (((b * 64 + hh) * 64 + ww) << 4) +
                                     half * 8);
            *(float4*)(As + px * LDA + t * 16 + half * 8) = v;
        } else {
            int z = s - 1152;  // < 128
            int px = z >> 1, half = z & 1;
            *(float4*)(As + px * LDA + 144 + half * 8) =
                make_float4(0.f, 0.f, 0.f, 0.f);
        }
    }
    __syncthreads();

    f32x4 acc[4][2];
#pragma unroll
    for (int ms = 0; ms < 4; ++ms)
#pragma unroll
        for (int ns = 0; ns < 2; ++ns) acc[ms][ns] = (f32x4){0.f, 0.f, 0.f, 0.f};

#pragma unroll
    for (int k = 0; k < 5; ++k) {
        short8 af[4];
#pragma unroll
        for (int ms = 0; ms < 4; ++ms)
            af[ms] = *(const short8*)(As + (ms * 16 + r) * LDA + k * 32 + q * 8);
#pragma unroll
        for (int ms = 0; ms < 4; ++ms)
#pragma unroll
            for (int ns = 0; ns < 2; ++ns)
                acc[ms][ns] = __builtin_amdgcn_mfma_f32_16x16x32_bf16(
                    af[ms], bf1[k][ns], acc[ms][ns], 0, 0, 0);
    }

#pragma unroll
    for (int ns = 0; ns < 2; ++ns) {
        int co = wv * 32 + ns * 16 + r;
        float bv = bias[co];
#pragma unroll
        for (int ms = 0; ms < 4; ++ms)
#pragma unroll
            for (int rg = 0; rg < 4; ++rg) {
                int px = ms * 16 + q * 4 + rg;
                int pix = (b * 64 + h0) * 64 + px;
                out[(size_t)pix * 128 + co] = f2bf(gelu_f(acc[ms][ns][rg] + bv));
            }
    }
}

// ---------------------------------------------------------------------------
// 3x3 128->128 conv + GELU via MFMA; halo staged once; weight frags ping-pong
// prefetched one k-group ahead (global->VGPR overlaps the 8 MFMAs).
// GATHER: A-pixels fetched through the packed VQ result (fused codebook
// gather). FUSE: dec2 (1x1 conv 128->16 + sigmoid) fused into the epilogue,
// writing the final NCHW fp32 output.
template <bool OUT_BF16, bool GATHER, bool FUSE>
__global__ __launch_bounds__(256, 2) void conv3x3_mfma_kernel(
    const unsigned short* __restrict__ in,   // NHWC acts, or embbf if GATHER
    const unsigned long long* __restrict__ gidx,  // packed VQ result or null
    const unsigned short* __restrict__ wtb,  // [9][co][ci] bf16
    const float* __restrict__ bias,          // [128]
    const float* __restrict__ w2,            // [16][128] fp32 (FUSE)
    const float* __restrict__ b2,            // [16] fp32 (FUSE)
    void* __restrict__ out_) {               // NHWC bf16/fp32, or NCHW if FUSE
    constexpr int LDC = 136;
    __shared__ __align__(16) unsigned short As[3 * 66 * LDC];  // 53856 B
    __shared__ __align__(16) float ws2[FUSE ? 2048 : 4];
    int tid = threadIdx.x;
    int wv = tid >> 6, lane = tid & 63;
    int r = lane & 15, q = lane >> 4;
    int h0 = blockIdx.x & 63, b = blockIdx.x >> 6;

    constexpr int NJ = FUSE ? 15 : 13;
    for (int j = 0; j < NJ; ++j) {
        int s = tid + j * 256;
        if (s < 3168) {
            int col = s >> 4, chunk = s & 15;
            int ry = col / 66, cx = col % 66;
            int hh = h0 - 1 + ry, ww = cx - 1;
            float4 v = make_float4(0.f, 0.f, 0.f, 0.f);
            if ((unsigned)hh < 64u && (unsigned)ww < 64u) {
                int pix = (b * 64 + hh) * 64 + ww;
                const unsigned short* src;
                if (GATHER) {
                    int k = 8191 - (int)(unsigned)(gidx[pix] & 0xFFFFFFFFu);
                    src = in + (size_t)k * 128;
                } else {
                    src = in + (size_t)pix * 128;
                }
                v = *(const float4*)(src + chunk * 8);
            }
            *(float4*)(As + col * LDC + chunk * 8) = v;
        } else if (FUSE && s < 3680) {
            int i = s - 3168;  // < 512 float4 slots
            ((float4*)ws2)[i] = ((const float4*)w2)[i];
        }
    }
    __syncthreads();

    f32x4 acc[4][2];
#pragma unroll
    for (int ms = 0; ms < 4; ++ms)
#pragma unroll
        for (int ns = 0; ns < 2; ++ns) acc[ms][ns] = (f32x4){0.f, 0.f, 0.f, 0.f};

    // weight ping-pong: groups g = t*4 + k, prefetch g+1 during g's MFMAs
    const unsigned short* wbase = wtb + (wv * 32 + r) * 128 + q * 8;
    short8 bfp[2][2];
    bfp[0][0] = *(const short8*)(wbase);
    bfp[0][1] = *(const short8*)(wbase + 2048);
    int gcur = 0;
    for (int t = 0; t < 9; ++t) {
        int dy = t / 3, dx = t % 3;
#pragma unroll
        for (int k = 0; k < 4; ++k) {
            int cur = gcur & 1, nxt = cur ^ 1;
            if (gcur < 35) {
                int g1 = gcur + 1;
                int t1 = g1 >> 2, k1 = g1 & 3;
                const unsigned short* wp = wbase + t1 * 16384 + k1 * 32;
                bfp[nxt][0] = *(const short8*)(wp);
                bfp[nxt][1] = *(const short8*)(wp + 2048);
            }
            short8 af[4];
#pragma unroll
            for (int ms = 0; ms < 4; ++ms) {
                int col = dy * 66 + ms * 16 + r + dx;
                af[ms] = *(const short8*)(As + col * LDC + k * 32 + q * 8);
            }
#pragma unroll
            for (int ms = 0; ms < 4; ++ms)
#pragma unroll
                for (int ns = 0; ns < 2; ++ns)
                    acc[ms][ns] = __builtin_amdgcn_mfma_f32_16x16x32_bf16(
                        af[ms], bfp[cur][ns], acc[ms][ns], 0, 0, 0);
            ++gcur;
        }
    }

    if (!FUSE) {
#pragma unroll
        for (int ns = 0; ns < 2; ++ns) {
            int co = wv * 32 + ns * 16 + r;
            float bv = bias[co];
#pragma unroll
            for (int ms = 0; ms < 4; ++ms)
#pragma unroll
                for (int rg = 0; rg < 4; ++rg) {
                    int px = ms * 16 + q * 4 + rg;
                    int pix = (b * 64 + h0) * 64 + px;
                    float g = gelu_f(acc[ms][ns][rg] + bv);
                    if (OUT_BF16)
                        ((unsigned short*)out_)[(size_t)pix * 128 + co] = f2bf(g);
                    else
                        ((float*)out_)[(size_t)pix * 128 + co] = g;
                }
        }
    } else {
        // bias+GELU -> LDS (reuse As as float[64][130]), then 1x1+sigmoid
        __syncthreads();  // all af reads done before overwrite
        float* gbuf = (float*)As;
#pragma unroll
        for (int ns = 0; ns < 2; ++ns) {
            int co = wv * 32 + ns * 16 + r;
            float bv = bias[co];
#pragma unroll
            for (int ms = 0; ms < 4; ++ms)
#pragma unroll
                for (int rg = 0; rg < 4; ++rg) {
                    int px = ms * 16 + q * 4 + rg;
                    gbuf[px * 130 + co] = gelu_f(acc[ms][ns][rg] + bv);
                }
        }
        __syncthreads();
        int w_ = tid & 63, c0 = (tid >> 6) * 4;
        float a4[4] = {b2[c0], b2[c0 + 1], b2[c0 + 2], b2[c0 + 3]};
#pragma unroll 1
        for (int ci = 0; ci < 128; ci += 2) {
            float2 yv = *(const float2*)&gbuf[w_ * 130 + ci];
#pragma unroll
            for (int jc = 0; jc < 4; ++jc) {
                float2 wv2 = *(const float2*)&ws2[(c0 + jc) * 128 + ci];
                a4[jc] += yv.x * wv2.x + yv.y * wv2.y;
            }
        }
        float* outp = (float*)out_;
#pragma unroll
        for (int jc = 0; jc < 4; ++jc) {
            float v = 1.0f / (1.0f + expf(-a4[jc]));
            outp[(((size_t)b * 16 + c0 + jc) * 64 + h0) * 64 + w_] = v;
        }
    }
}

// ---------------------------------------------------------------------------
// VQ argmin via bf16 MFMA. LDS-STAGED GEMM BUILD v8 (= v7 + conflict-free
// fragment layout). v7 landed 137->80us (occupancy 34%, MfmaUtil 37%) but
// SQ_LDS_BANK_CONFLICT hit 8.39M (+4 cyc on each of 2.1M ds_read_b128: the
// [ns][r][q] layout strides 64B per r-lane = 8-way quarter-wave conflict).
// v8: embq reordered to [kk][ns][q][r] so lane l reads byte l*16 -> 64
// lanes read 1024 contiguous bytes, conflict-free. Staging stays linear
// global_load_lds (permutation baked into the GLOBAL source = rule-21-safe).
//  - per tile: 16 linear 1-KB DMAs double-buffered; one barrier per tile.
//  - wave geometry 32px x 32codes: acc[2][2]=16 AGPR, af[4][2]=32 regs.
//  - LDS 32 KB, ~44 arch VGPR -> 4 blocks/CU, grid = one round exactly.
// Two 32-tile passes, 11-bit key / 0xFFFFF800 mask; code = kbase +
// pass*2048 + cand. Cross-block: atomicMax on (sortable<<32 | 8191-code).
__global__ __launch_bounds__(256, 2) void vq_mfma_kernel(
    const unsigned short* __restrict__ flatbf,  // [N][128] bf16
    const unsigned short* __restrict__ embq,    // fragment-ordered codebook
    const float* __restrict__ e2n,              // [K] fp32, -||e||^2/2
    unsigned long long* __restrict__ partial) { // [N] packed, zero-inited
    __shared__ __align__(16) unsigned short Bs[2][8192];  // 2 x 16 KB
    int tid = threadIdx.x;
    int wv = tid >> 6, lane = tid & 63;
    int r = lane & 15, q = lane >> 4;
    int p_h = wv & 1;   // pixel half: rows p_h*32 + ms*16 + ...
    int c_s = wv >> 1;  // code half of each 64-code tile
    int half = blockIdx.x & 1;
    int m0 = (blockIdx.x >> 1) * 64;
    int kbase = half * 4096;
    int t0 = half * 64;  // first tile index

    // A: 32 px x 128 dims preloaded to regs (8 gather loads, once)
    short8 af[4][2];
#pragma unroll
    for (int kk = 0; kk < 4; ++kk)
#pragma unroll
        for (int ms = 0; ms < 2; ++ms)
            af[kk][ms] = *(const short8*)(
                flatbf + (size_t)(m0 + p_h * 32 + ms * 16 + r) * 128 +
                kk * 32 + q * 8);

    const float* e2p = e2n + kbase + c_s * 32 + r;
    float e2a = e2p[0], e2b = e2p[16];  // it=0 init values
    float e2nx0 = 0.f, e2nx1 = 0.f;

    // stage tile 0 into Bs[0]
    {
        const unsigned short* src = embq + (size_t)t0 * 8192;
#pragma unroll
        for (int j = 0; j < 4; ++j) {
            int o = (j * 4 + wv) * 512;  // shorts (1 KB per DMA)
            gload_lds16(src + o + lane * 8, &Bs[0][o]);
        }
    }

    float best[2][4];
#pragma unroll
    for (int ms = 0; ms < 2; ++ms)
#pragma unroll
        for (int rg = 0; rg < 4; ++rg) best[ms][rg] = -3.4e38f;

    __syncthreads();  // tile 0 ready (barrier drains vmcnt)

    f32x4 acc[2][2];
#pragma unroll
    for (int ms = 0; ms < 2; ++ms) {
        acc[ms][0] = (f32x4){e2a, e2a, e2a, e2a};
        acc[ms][1] = (f32x4){e2b, e2b, e2b, e2b};
    }

    int cur = 0;
#pragma unroll 1
    for (int it = 0; it < 64; ++it) {
        if (it < 63) {  // stage tile it+1 into the other buffer
            const unsigned short* src = embq + (size_t)(t0 + it + 1) * 8192;
            unsigned short* dst = &Bs[cur ^ 1][0];
#pragma unroll
            for (int j = 0; j < 4; ++j) {
                int o = (j * 4 + wv) * 512;
                gload_lds16(src + o + lane * 8, dst + o);
            }
            // e2 for next tile (consumed at reinit, ~whole tile of lead)
            e2nx0 = e2p[(it + 1) * 64];
            e2nx1 = e2p[(it + 1) * 64 + 16];
        }
        const unsigned short* bb = &Bs[cur][0];
#pragma unroll
        for (int kk = 0; kk < 4; ++kk) {
            // [kk][ns][q][r] layout: lane l reads byte l*16 of its ns-block
            short8 bf0 = *(const short8*)(bb + kk * 2048 + (c_s * 2) * 512 +
                                          q * 128 + r * 8);
            short8 bf1 = *(const short8*)(bb + kk * 2048 + (c_s * 2 + 1) * 512 +
                                          q * 128 + r * 8);
#pragma unroll
            for (int ms = 0; ms < 2; ++ms) {
                acc[ms][0] = __builtin_amdgcn_mfma_f32_16x16x32_bf16(
                    af[kk][ms], bf0, acc[ms][0], 0, 0, 0);
                acc[ms][1] = __builtin_amdgcn_mfma_f32_16x16x32_bf16(
                    af[kk][ms], bf1, acc[ms][1], 0, 0, 0);
            }
        }
        // epilogue: pack 11-bit key (it5,c_s,ns,r), running max
        unsigned kb = (unsigned)(2047 - ((it & 31) * 64 + c_s * 32 + r));
#pragma unroll
        for (int ms = 0; ms < 2; ++ms)
#pragma unroll
            for (int rg = 0; rg < 4; ++rg) {
                float u0 = __uint_as_float(
                    (__float_as_uint(acc[ms][0][rg]) & 0xFFFFF800u) | kb);
                float u1 = __uint_as_float(
                    (__float_as_uint(acc[ms][1][rg]) & 0xFFFFF800u) |
                    (kb - 16u));
                best[ms][rg] = fmaxf(best[ms][rg], fmaxf(u0, u1));
            }
        if ((it & 31) == 31) {  // pass end: merge r-lanes, atomic, reset
#pragma unroll
            for (int ms = 0; ms < 2; ++ms)
#pragma unroll
                for (int rg = 0; rg < 4; ++rg) {
                    float v = best[ms][rg];
#pragma unroll
                    for (int m = 1; m < 16; m <<= 1)
                        v = fmaxf(v, __shfl_xor(v, m));
                    if (r == 0) {
                        unsigned bits = __float_as_uint(v);
                        int cand = 2047 - (int)(bits & 2047u);
                        int code = kbase + (it >> 5) * 2048 + cand;
                        unsigned sb = (bits & 0x80000000u) ? ~bits
                                                           : (bits | 0x80000000u);
                        unsigned long long packed =
                            ((unsigned long long)sb << 32) |
                            (unsigned)(8191 - code);
                        atomicMax(
                            partial + m0 + p_h * 32 + ms * 16 + q * 4 + rg,
                            packed);
                    }
                    best[ms][rg] = -3.4e38f;
                }
        }
        if (it < 63) {  // reinit acc for next tile's codes
#pragma unroll
            for (int ms = 0; ms < 2; ++ms) {
                acc[ms][0] = (f32x4){e2nx0, e2nx0, e2nx0, e2nx0};
                acc[ms][1] = (f32x4){e2nx1, e2nx1, e2nx1, e2nx1};
            }
        }
        __syncthreads();  // staging done + all reads of Bs[cur] done
        cur ^= 1;
    }
}

// ---------------------------------------------------------------------------
extern "C" void kernel_launch(void* const* d_in, const int* in_sizes, int n_in,
                              void* d_out, int out_size, void* d_ws,
                              size_t ws_size, hipStream_t stream) {
    const float* x = (const float*)d_in[0];
    const float* ew1 = (const float*)d_in[1];
    const float* eb1 = (const float*)d_in[2];
    const float* ew2 = (const float*)d_in[3];
    const float* eb2 = (const float*)d_in[4];
    const float* embed = (const float*)d_in[5];
    const float* dw1 = (const float*)d_in[6];
    const float* db1 = (const float*)d_in[7];
    const float* dw2 = (const float*)d_in[8];
    const float* db2 = (const float*)d_in[9];
    float* out = (float*)d_out;

    float* e2n = (float*)d_ws;                             // 8192 f
    unsigned long long* partial =
        (unsigned long long*)(e2n + 8192);                 // 32768 u64
    unsigned short* xtbf = (unsigned short*)(partial + 32768);  // 524288 us
    unsigned short* wtb1b = xtbf + 524288;                 // 20480 us
    unsigned short* wtbf2 = wtb1b + 20480;                 // 147456 us
    unsigned short* wtbf3 = wtbf2 + 147456;                // 147456 us
    unsigned short* embbf = wtbf3 + 147456;                // 1048576 us
    unsigned short* abf = embbf + 1048576;                 // 4194304 us
    unsigned short* flatbf = abf + 4194304;                // 4194304 us
    unsigned short* embq = flatbf + 4194304;               // 1048576 us

    prep_kernel<<<4976, 256, 0, stream>>>(x, ew1, ew2, dw1, embed, xtbf, wtbf2,
                                          wtbf3, e2n, embbf, wtb1b, partial,
                                          embq);
    conv1_mfma_kernel<<<512, 256, 0, stream>>>(xtbf, wtb1b, eb1, abf);
    conv3x3_mfma_kernel<true, false, false><<<512, 256, 0, stream>>>(
        abf, nullptr, wtbf2, eb2, nullptr, nullptr, flatbf);
    vq_mfma_kernel<<<1024, 256, 0, stream>>>(flatbf, embq, e2n, partial);
    conv3x3_mfma_kernel<false, true, true><<<512, 256, 0, stream>>>(
        embbf, partial, wtbf3, db1, dw2, db2, out);
}